// Round 2
// baseline (1269.131 us; speedup 1.0000x reference)
//
#include <hip/hip_runtime.h>

#define NN 100000   // nodes
#define NE 1600000  // edges
#define NR 8        // relations
#define DD 128      // feature dim
#define NKEY (NN * NR)           // 800000 (dst,rel) keys
#define NBLK ((NKEY + 1023) / 1024)  // 782 scan blocks

typedef __attribute__((ext_vector_type(8))) short short8;
typedef __attribute__((ext_vector_type(4))) float f32x4;

__device__ __forceinline__ float bf2f(unsigned short u) {
  union { unsigned int i; float f; } c; c.i = ((unsigned int)u) << 16; return c.f;
}
__device__ __forceinline__ unsigned short f2bf(float f) {
  union { float f; unsigned int i; } c; c.f = f;
  unsigned int u = c.i;
  return (unsigned short)((u + 0x7FFFu + ((u >> 16) & 1u)) >> 16);  // RNE
}

// ---- preprocessing ----------------------------------------------------------

__global__ __launch_bounds__(256) void k_cast(
    const float* __restrict__ x, unsigned short* __restrict__ xb) {
  int i = blockIdx.x * 256 + threadIdx.x;          // over N*D/4
  if (i < NN * DD / 4) {
    float4 f = ((const float4*)x)[i];
    ushort4 u;
    u.x = f2bf(f.x); u.y = f2bf(f.y); u.z = f2bf(f.z); u.w = f2bf(f.w);
    ((ushort4*)xb)[i] = u;
  }
}

// wbf[layer][rb][n][k] = W[rb][k][n]  (rb==8 -> root), bf16
__global__ __launch_bounds__(256) void k_wtrans(
    const float* __restrict__ W1, const float* __restrict__ root1,
    const float* __restrict__ W2, const float* __restrict__ root2,
    unsigned short* __restrict__ wbf) {
  int idx = blockIdx.x * 256 + threadIdx.x;        // 2*9*16384 total
  int layer = idx / (9 * 16384);
  int rem = idx % (9 * 16384);
  int r = rem / 16384;
  int nk = rem % 16384;
  int n = nk >> 7, k = nk & 127;
  float v;
  if (r < 8) v = (layer ? W2 : W1)[r * 16384 + k * 128 + n];
  else       v = (layer ? root2 : root1)[k * 128 + n];
  wbf[idx] = f2bf(v);
}

__global__ __launch_bounds__(256) void k_zero(int* __restrict__ p, int n) {
  int i = blockIdx.x * 256 + threadIdx.x;
  if (i < n) p[i] = 0;
}

__global__ __launch_bounds__(256) void k_count(
    const int* __restrict__ ei, const int* __restrict__ et, int* __restrict__ cnt) {
  int e = blockIdx.x * 256 + threadIdx.x;
  if (e < NE) {
    int dst = ei[NE + e];
    int r = et[e];
    atomicAdd(&cnt[dst * NR + r], 1);
  }
}

// hierarchical exclusive scan over NKEY elements
__global__ __launch_bounds__(1024) void k_scan1(
    const int* __restrict__ cnt, int* __restrict__ offs, int* __restrict__ bsum) {
  __shared__ int sd[1024];
  int t = threadIdx.x, b = blockIdx.x;
  int i = b * 1024 + t;
  int v = (i < NKEY) ? cnt[i] : 0;
  sd[t] = v;
  __syncthreads();
  for (int o = 1; o < 1024; o <<= 1) {
    int tv = (t >= o) ? sd[t - o] : 0;
    __syncthreads();
    sd[t] += tv;
    __syncthreads();
  }
  if (i < NKEY) offs[i] = sd[t] - v;               // block-local exclusive
  if (t == 1023) bsum[b] = sd[t];
}

__global__ __launch_bounds__(1024) void k_scan2(int* __restrict__ bsum) {
  __shared__ int sd[1024];
  int t = threadIdx.x;
  int v = (t < NBLK) ? bsum[t] : 0;
  sd[t] = v;
  __syncthreads();
  for (int o = 1; o < 1024; o <<= 1) {
    int tv = (t >= o) ? sd[t - o] : 0;
    __syncthreads();
    sd[t] += tv;
    __syncthreads();
  }
  if (t < NBLK) bsum[t] = sd[t] - v;               // exclusive block bases
}

__global__ __launch_bounds__(256) void k_scan3(
    int* __restrict__ offs, const int* __restrict__ bsum) {
  int i = blockIdx.x * 256 + threadIdx.x;
  if (i < NKEY) offs[i] += bsum[i >> 10];
  if (i == 0) offs[NKEY] = NE;                     // total is always NE
}

__global__ __launch_bounds__(256) void k_csr(
    const int* __restrict__ ei, const int* __restrict__ et,
    const int* __restrict__ offs, int* __restrict__ fill, int* __restrict__ csr) {
  int e = blockIdx.x * 256 + threadIdx.x;
  if (e < NE) {
    int src = ei[e];
    int key = ei[NE + e] * NR + et[e];
    int pos = offs[key] + atomicAdd(&fill[key], 1);
    csr[pos] = src;
  }
}

// ---- fused per-layer kernel -------------------------------------------------
// Block = 256 thr (4 waves) owns 64 dst nodes. Per relation: each wave
// mean-aggregates its 16 rows from L2/L3-resident xb into wave-private LDS,
// then MFMA-multiplies by W_r, accumulating C frags across relations + root.
template <int RELU, int OUTBF>
__global__ __launch_bounds__(256) void k_fused(
    const unsigned short* __restrict__ xb,   // [N][128] bf16
    const unsigned short* __restrict__ wl,   // [9][128][128] n-major bf16
    const int* __restrict__ offs, const int* __restrict__ csr,
    const float* __restrict__ bias, void* __restrict__ outp) {
  __shared__ unsigned short sA[4][16][136];        // +8 pad breaks bank aliasing
  const int w = threadIdx.x >> 6;
  const int lane = threadIdx.x & 63;
  const int m = lane & 15, q = lane >> 4;
  const int half = lane >> 5, li = lane & 31;
  const int row0 = blockIdx.x * 64 + w * 16;

  f32x4 acc[8];
#pragma unroll
  for (int nt = 0; nt < 8; nt++) acc[nt] = (f32x4){0.f, 0.f, 0.f, 0.f};

  for (int r = 0; r < NR; r++) {
    // phase A: aggregate 16 rows (2 edges in flight: 32 lanes per 256B row)
    for (int i = 0; i < 16; i++) {
      int node = row0 + i;
      if (node >= NN) node = NN - 1;
      int key = node * NR + r;
      int beg = offs[key], endv = offs[key + 1];
      int c = endv - beg;
      float norm = 1.0f / (float)(c > 1 ? c : 1);
      f32x4 a4 = (f32x4){0.f, 0.f, 0.f, 0.f};
      for (int e = beg + half; e < endv; e += 2) {
        int s = csr[e];
        ushort4 v = *(const ushort4*)(xb + (size_t)s * DD + 4 * li);
        a4[0] += bf2f(v.x); a4[1] += bf2f(v.y);
        a4[2] += bf2f(v.z); a4[3] += bf2f(v.w);
      }
#pragma unroll
      for (int j = 0; j < 4; j++) a4[j] += __shfl_xor(a4[j], 32);
      if (half == 0) {
        ushort4 o;
        o.x = f2bf(a4[0] * norm); o.y = f2bf(a4[1] * norm);
        o.z = f2bf(a4[2] * norm); o.w = f2bf(a4[3] * norm);
        *(ushort4*)(&sA[w][i][4 * li]) = o;
      }
    }
    // phase B: wave-private LDS -> MFMA (no __syncthreads needed)
    short8 a[4];
#pragma unroll
    for (int ks = 0; ks < 4; ks++)
      a[ks] = *(const short8*)(&sA[w][m][ks * 32 + q * 8]);
    const unsigned short* wr = wl + r * DD * DD;
#pragma unroll
    for (int nt = 0; nt < 8; nt++) {
      const unsigned short* wp = wr + (nt * 16 + m) * DD + q * 8;
#pragma unroll
      for (int ks = 0; ks < 4; ks++) {
        short8 b = *(const short8*)(wp + ks * 32);
        acc[nt] = __builtin_amdgcn_mfma_f32_16x16x32_bf16(a[ks], b, acc[nt], 0, 0, 0);
      }
    }
  }
  // root: A frags straight from xb (identity "aggregation")
  {
    int row = row0 + m;
    if (row >= NN) row = NN - 1;
    short8 a[4];
#pragma unroll
    for (int ks = 0; ks < 4; ks++)
      a[ks] = *(const short8*)(xb + (size_t)row * DD + ks * 32 + q * 8);
    const unsigned short* wr = wl + 8 * DD * DD;
#pragma unroll
    for (int nt = 0; nt < 8; nt++) {
      const unsigned short* wp = wr + (nt * 16 + m) * DD + q * 8;
#pragma unroll
      for (int ks = 0; ks < 4; ks++) {
        short8 b = *(const short8*)(wp + ks * 32);
        acc[nt] = __builtin_amdgcn_mfma_f32_16x16x32_bf16(a[ks], b, acc[nt], 0, 0, 0);
      }
    }
  }
  // epilogue: C/D layout col = lane&15, row = q*4 + i
#pragma unroll
  for (int nt = 0; nt < 8; nt++) {
    float bv = bias[nt * 16 + m];
#pragma unroll
    for (int i = 0; i < 4; i++) {
      int row = row0 + q * 4 + i;
      if (row < NN) {
        float vv = acc[nt][i] + bv;
        if (RELU) vv = fmaxf(vv, 0.f);
        if (OUTBF)
          ((unsigned short*)outp)[(size_t)row * DD + nt * 16 + m] = f2bf(vv);
        else
          ((float*)outp)[(size_t)row * DD + nt * 16 + m] = vv;
      }
    }
  }
}

// ---- launch -----------------------------------------------------------------

extern "C" void kernel_launch(void* const* d_in, const int* in_sizes, int n_in,
                              void* d_out, int out_size, void* d_ws, size_t ws_size,
                              hipStream_t stream) {
  const float* x     = (const float*)d_in[0];
  const int*   ei    = (const int*)d_in[1];
  const int*   et    = (const int*)d_in[2];
  const float* W1    = (const float*)d_in[3];
  const float* root1 = (const float*)d_in[4];
  const float* b1    = (const float*)d_in[5];
  const float* W2    = (const float*)d_in[6];
  const float* root2 = (const float*)d_in[7];
  const float* b2    = (const float*)d_in[8];
  float* out = (float*)d_out;

  char* p = (char*)d_ws;
  unsigned short* xb1 = (unsigned short*)p; p += (size_t)NN * DD * 2;       // 25.6 MB
  unsigned short* xb2 = (unsigned short*)p; p += (size_t)NN * DD * 2;       // 25.6 MB
  unsigned short* wbf = (unsigned short*)p; p += (size_t)2 * 9 * DD * DD * 2;
  int* cnt  = (int*)p; p += (size_t)NKEY * 4;                               // 3.2 MB
  int* fill = (int*)p; p += (size_t)NKEY * 4;                               // 3.2 MB (contiguous after cnt)
  int* offs = (int*)p; p += (size_t)(NKEY + 16) * 4;                        // 3.2 MB
  int* bsum = (int*)p; p += (size_t)1024 * 4;
  int* csr  = (int*)p; p += (size_t)NE * 4;                                 // 6.4 MB
  // total ~= 67.4 MB

  k_cast<<<(NN * DD / 4 + 255) / 256, 256, 0, stream>>>(x, xb1);
  k_wtrans<<<(2 * 9 * 16384) / 256, 256, 0, stream>>>(W1, root1, W2, root2, wbf);
  k_zero<<<(2 * NKEY + 255) / 256, 256, 0, stream>>>(cnt, 2 * NKEY);  // cnt+fill contiguous
  k_count<<<(NE + 255) / 256, 256, 0, stream>>>(ei, et, cnt);
  k_scan1<<<NBLK, 1024, 0, stream>>>(cnt, offs, bsum);
  k_scan2<<<1, 1024, 0, stream>>>(bsum);
  k_scan3<<<(NKEY + 255) / 256, 256, 0, stream>>>(offs, bsum);
  k_csr<<<(NE + 255) / 256, 256, 0, stream>>>(ei, et, offs, fill, csr);

  dim3 fgrid((NN + 63) / 64);
  k_fused<1, 1><<<fgrid, 256, 0, stream>>>(xb1, wbf, offs, csr, b1, (void*)xb2);
  k_fused<0, 0><<<fgrid, 256, 0, stream>>>(xb2, wbf + 9 * DD * DD, offs, csr, b2, (void*)out);
}